// Round 1
// baseline (483.904 us; speedup 1.0000x reference)
//
#include <hip/hip_runtime.h>
#include <stdint.h>

typedef float f32x4 __attribute__((ext_vector_type(4)));

#define FP8_MAX_V 448.0f

// Pack 4 floats -> 4 OCP e4m3fn bytes, RNE, after reference-matching clip.
__device__ __forceinline__ uint32_t pack4_fp8(float a, float b, float c, float d) {
    a = fminf(fmaxf(a, -FP8_MAX_V), FP8_MAX_V);
    b = fminf(fmaxf(b, -FP8_MAX_V), FP8_MAX_V);
    c = fminf(fmaxf(c, -FP8_MAX_V), FP8_MAX_V);
    d = fminf(fmaxf(d, -FP8_MAX_V), FP8_MAX_V);
    int v = 0;
    v = __builtin_amdgcn_cvt_pk_fp8_f32(a, b, v, false);  // bytes 0,1
    v = __builtin_amdgcn_cvt_pk_fp8_f32(c, d, v, true);   // bytes 2,3
    return (uint32_t)v;
}

// fp32 -> fp8 e4m3fn per-tensor static quant. Exact division by scale (matches
// the reference's t/scale rounding), then HW RNE conversion.
__global__ void quant_fp8_kernel(const float* __restrict__ in,
                                 uint32_t* __restrict__ out,
                                 const float* __restrict__ scale_ptr,
                                 long long n4) {
    const float s = scale_ptr[0];
    long long i = (long long)blockIdx.x * blockDim.x + threadIdx.x;
    const long long stride = (long long)gridDim.x * blockDim.x;
    const float4* in4 = (const float4*)in;
    for (; i < n4; i += stride) {
        float4 v = in4[i];
        out[i] = pack4_fp8(v.x / s, v.y / s, v.z / s, v.w / s);
    }
}

// C[M,N] = (qA[M,K] . qB[N,K]^T) * (s_in*s_w) + bias
// 128x128 tile, BK=128 (bytes), 4 waves (2x2), each wave 64x64 out.
// LDS staged via global_load_lds width=16 (linear dest), XOR-16 swizzle
// applied on the global SOURCE column and on the ds_read column (rule #21).
__global__ __launch_bounds__(256) void gemm_fp8_kernel(
    const uint8_t* __restrict__ qA,   // [M][K] fp8
    const uint8_t* __restrict__ qB,   // [N][K] fp8
    const float* __restrict__ bias,   // [N]
    const float* __restrict__ s_in_p,
    const float* __restrict__ s_w_p,
    float* __restrict__ C,            // [M][N] fp32
    int M, int N, int K) {
    __shared__ uint8_t lsA[128 * 128];
    __shared__ uint8_t lsB[128 * 128];

    const int tid = threadIdx.x;
    const int w   = tid >> 6;   // wave 0..3
    const int l   = tid & 63;   // lane
    const int wr  = w >> 1;     // wave row (0..1)
    const int wc  = w & 1;      // wave col (0..1)

    const int bm = blockIdx.y << 7;
    const int bn = blockIdx.x << 7;

    const float outscale = s_in_p[0] * s_w_p[0];

    f32x4 acc[4][4];
#pragma unroll
    for (int i = 0; i < 4; ++i)
#pragma unroll
        for (int j = 0; j < 4; ++j)
            acc[i][j] = (f32x4){0.f, 0.f, 0.f, 0.f};

    // Staging geometry: one global_load_lds(16B) per lane covers 8 rows of the
    // 128B-wide tile: row = base + (l>>3), bytes [(l&7)*16, +16).
    // Source column pre-swizzled so LDS(row, b) = A[row][b ^ ((row&7)<<4)].
    const int srow = l >> 3;                         // 0..7
    const int scol = (((l & 7) ^ srow) << 4);        // swizzled src col
    const int rsw  = (l & 7) << 4;                   // read swizzle ((row&7)<<4 with row&7==l&7)
    const int lg   = l >> 4;                         // lane group 0..3
    const int lr   = l & 15;                         // lane row/col in fragment

    const uint8_t* srcA0 = qA + (size_t)(bm + w * 32 + srow) * K + scol;
    const uint8_t* srcB0 = qB + (size_t)(bn + w * 32 + srow) * K + scol;

    const int nkt = K >> 7;
    for (int kt = 0; kt < nkt; ++kt) {
        const int kb = kt << 7;
        // stage A: wave w owns tile rows [w*32, w*32+32)
#pragma unroll
        for (int i = 0; i < 4; ++i) {
            __builtin_amdgcn_global_load_lds(
                (const __attribute__((address_space(1))) void*)(srcA0 + (size_t)i * 8 * K + kb),
                (__attribute__((address_space(3))) void*)(lsA + (w * 32 + i * 8) * 128),
                16, 0, 0);
        }
#pragma unroll
        for (int i = 0; i < 4; ++i) {
            __builtin_amdgcn_global_load_lds(
                (const __attribute__((address_space(1))) void*)(srcB0 + (size_t)i * 8 * K + kb),
                (__attribute__((address_space(3))) void*)(lsB + (w * 32 + i * 8) * 128),
                16, 0, 0);
        }
        __syncthreads();  // drains vmcnt before barrier

#pragma unroll
        for (int kk = 0; kk < 4; ++kk) {   // K=32 sub-steps within BK=128
            const int cswz = ((kk << 5) + (lg << 3)) ^ rsw;
            long a[4], b[4];
#pragma unroll
            for (int mi = 0; mi < 4; ++mi)
                a[mi] = *(const long*)(lsA + ((wr * 64 + mi * 16 + lr) << 7) + cswz);
#pragma unroll
            for (int ni = 0; ni < 4; ++ni)
                b[ni] = *(const long*)(lsB + ((wc * 64 + ni * 16 + lr) << 7) + cswz);
#pragma unroll
            for (int mi = 0; mi < 4; ++mi)
#pragma unroll
                for (int ni = 0; ni < 4; ++ni)
                    acc[mi][ni] = __builtin_amdgcn_mfma_f32_16x16x32_fp8_fp8(
                        a[mi], b[ni], acc[mi][ni], 0, 0, 0);
        }
        __syncthreads();
    }

    // Epilogue: C/D layout col=lane&15, row=(lane>>4)*4+reg (m89, dtype-indep).
    const int crow0 = bm + wr * 64 + lg * 4;
    const int ccol0 = bn + wc * 64 + lr;
#pragma unroll
    for (int ni = 0; ni < 4; ++ni) {
        const int col = ccol0 + ni * 16;
        const float bv = bias[col];
#pragma unroll
        for (int mi = 0; mi < 4; ++mi) {
            const int row = crow0 + mi * 16;
#pragma unroll
            for (int r = 0; r < 4; ++r)
                C[(size_t)(row + r) * N + col] = acc[mi][ni][r] * outscale + bv;
        }
    }
}

extern "C" void kernel_launch(void* const* d_in, const int* in_sizes, int n_in,
                              void* d_out, int out_size, void* d_ws, size_t ws_size,
                              hipStream_t stream) {
    const float* x    = (const float*)d_in[0];
    const float* wt   = (const float*)d_in[1];
    const float* bias = (const float*)d_in[2];
    const float* s_in = (const float*)d_in[3];
    const float* s_w  = (const float*)d_in[4];
    float* out = (float*)d_out;

    const long long xe = in_sizes[0];            // M*K
    const long long we = in_sizes[1];            // N*K
    const int N = in_sizes[2];
    const int K = (int)(we / N);
    const int M = (int)(xe / K);

    uint8_t* qx = (uint8_t*)d_ws;                // M*K fp8
    uint8_t* qw = qx + xe;                       // N*K fp8

    quant_fp8_kernel<<<2048, 256, 0, stream>>>(x,  (uint32_t*)qx, s_in, xe >> 2);
    quant_fp8_kernel<<<2048, 256, 0, stream>>>(wt, (uint32_t*)qw, s_w,  we >> 2);

    dim3 grid(N / 128, M / 128);  // (112, 32)
    gemm_fp8_kernel<<<grid, 256, 0, stream>>>(qx, qw, bias, s_in, s_w, out, M, N, K);
}